// Round 1
// baseline (851.042 us; speedup 1.0000x reference)
//
#include <hip/hip_runtime.h>
#include <math.h>

// Problem constants (SelfAttentionBlock: B=8, C=512, H=W=32, E=512, 8 heads, 32 groups)
constexpr int Bn  = 8;
constexpr int Cc  = 512;
constexpr int Ss  = 1024;   // H*W
constexpr int Ee  = 512;
constexpr int nHd = 8;
constexpr int Hd  = 64;     // head dim
constexpr int Gg  = 32;
constexpr int Cpg = 16;     // channels per group = E/G

// ---------------------------------------------------------------------------
// K1: QKV projection.  x: [B][C][S] (input layout), W: [C][E], bias: [E]
// out: [B][nH][S][Hd]   (e = h*64 + d)
// Computes out[b][s][e] = sum_c x[b][c][s] * W[c][e] + bias[e]
// Both operands are K(=C)-major: A[c][s], W[c][e]. 64x64 tile, 4x4/thread.
// ---------------------------------------------------------------------------
__global__ __launch_bounds__(256) void qkv_kernel(
    const float* __restrict__ x, const float* __restrict__ Wm,
    const float* __restrict__ bias, float* __restrict__ out)
{
    const int b  = blockIdx.z;
    const int e0 = blockIdx.y * 64;
    const int s0 = blockIdx.x * 64;
    const float* A = x + (size_t)b * Cc * Ss;

    __shared__ float As[16][64];
    __shared__ float Ws[16][64];

    const int t  = threadIdx.x;
    const int tm = t & 15;   // s direction (4 rows)
    const int tn = t >> 4;   // e direction (4 cols)
    float acc[4][4] = {};

    for (int k0 = 0; k0 < Cc; k0 += 16) {
#pragma unroll
        for (int i = 0; i < 4; i++) {
            int idx = t + i * 256;          // 1024 elements each
            int c = idx >> 6, s = idx & 63;
            As[c][s] = A[(size_t)(k0 + c) * Ss + s0 + s];
            Ws[c][s] = Wm[(size_t)(k0 + c) * Ee + e0 + s];
        }
        __syncthreads();
#pragma unroll
        for (int c = 0; c < 16; c++) {
            const float4 a4 = *(const float4*)&As[c][tm * 4];
            const float4 w4 = *(const float4*)&Ws[c][tn * 4];
            const float av[4] = {a4.x, a4.y, a4.z, a4.w};
            const float wv[4] = {w4.x, w4.y, w4.z, w4.w};
#pragma unroll
            for (int i = 0; i < 4; i++)
#pragma unroll
                for (int j = 0; j < 4; j++)
                    acc[i][j] += av[i] * wv[j];
        }
        __syncthreads();
    }

    const int h = e0 >> 6;   // 64-wide e-tile lies inside one head
#pragma unroll
    for (int i = 0; i < 4; i++) {
        const int s = s0 + tm * 4 + i;
#pragma unroll
        for (int j = 0; j < 4; j++) {
            const int e = e0 + tn * 4 + j;
            const int d = e & 63;
            out[(((size_t)b * nHd + h) * Ss + s) * Hd + d] = acc[i][j] + bias[e];
        }
    }
}

// ---------------------------------------------------------------------------
// K2: flash-style attention.  q,k,v: [B*nH][S][Hd].  One block per (bh, 64-row
// q tile). Online softmax, K and V time-share one LDS tile (static LDS < 64KB).
// attn_out written as [B][S][E] (e = h*64+d) for the output projection GEMM.
// ---------------------------------------------------------------------------
__global__ __launch_bounds__(256) void attn_kernel(
    const float* __restrict__ q, const float* __restrict__ k,
    const float* __restrict__ v, float* __restrict__ attn_out)
{
    const int bh = blockIdx.y;
    const int s0 = blockIdx.x * 64;
    const float* qp = q + (size_t)bh * Ss * Hd;
    const float* kp = k + (size_t)bh * Ss * Hd;
    const float* vp = v + (size_t)bh * Ss * Hd;

    __shared__ float Qs[64][68];    // +4 pad: break stride-64 bank aliasing
    __shared__ float KVs[64][68];   // K during scores, V during accumulate
    __shared__ float Ps[64][68];    // scores / probabilities
    __shared__ float mrow[64], lrow[64], arow[64];

    const int t  = threadIdx.x;
    const int tm = t & 15, tn = t >> 4;

    // load Q tile (64x64 floats, float4-coalesced)
#pragma unroll
    for (int i = 0; i < 4; i++) {
        int f4 = t + i * 256;
        int r = f4 >> 4, c4 = f4 & 15;
        *(float4*)&Qs[r][c4 * 4] =
            *(const float4*)&qp[(size_t)(s0 + r) * Hd + c4 * 4];
    }
    if (t < 64) { mrow[t] = -INFINITY; lrow[t] = 0.0f; }

    float acc[4][4] = {};
    __syncthreads();

    for (int kt = 0; kt < 16; kt++) {
        // --- load K tile into KVs ---
#pragma unroll
        for (int i = 0; i < 4; i++) {
            int f4 = t + i * 256;
            int r = f4 >> 4, c4 = f4 & 15;
            *(float4*)&KVs[r][c4 * 4] =
                *(const float4*)&kp[(size_t)(kt * 64 + r) * Hd + c4 * 4];
        }
        __syncthreads();

        // --- scores: S = scale * Q @ K^T  (4x4 per thread, dot over 64) ---
        float sc[4][4] = {};
#pragma unroll
        for (int d4 = 0; d4 < 16; d4++) {
            float qv[4][4], kv[4][4];
#pragma unroll
            for (int i = 0; i < 4; i++) {
                float4 tmp = *(const float4*)&Qs[tm * 4 + i][d4 * 4];
                qv[i][0] = tmp.x; qv[i][1] = tmp.y; qv[i][2] = tmp.z; qv[i][3] = tmp.w;
            }
#pragma unroll
            for (int j = 0; j < 4; j++) {
                float4 tmp = *(const float4*)&KVs[tn * 4 + j][d4 * 4];
                kv[j][0] = tmp.x; kv[j][1] = tmp.y; kv[j][2] = tmp.z; kv[j][3] = tmp.w;
            }
#pragma unroll
            for (int i = 0; i < 4; i++)
#pragma unroll
                for (int j = 0; j < 4; j++)
#pragma unroll
                    for (int dd = 0; dd < 4; dd++)
                        sc[i][j] += qv[i][dd] * kv[j][dd];
        }
#pragma unroll
        for (int i = 0; i < 4; i++)
#pragma unroll
            for (int j = 0; j < 4; j++)
                Ps[tm * 4 + i][tn * 4 + j] = sc[i][j] * 0.125f;  // hd^-0.5
        __syncthreads();   // Ps complete; KVs (K) dead

        // --- load V tile into KVs (overlaps softmax latency) ---
#pragma unroll
        for (int i = 0; i < 4; i++) {
            int f4 = t + i * 256;
            int r = f4 >> 4, c4 = f4 & 15;
            *(float4*)&KVs[r][c4 * 4] =
                *(const float4*)&vp[(size_t)(kt * 64 + r) * Hd + c4 * 4];
        }
        // --- online softmax, one thread per q row ---
        if (t < 64) {
            float mold = mrow[t];
            float tmax = -INFINITY;
#pragma unroll 8
            for (int j = 0; j < 64; j++) tmax = fmaxf(tmax, Ps[t][j]);
            float mnew = fmaxf(mold, tmax);
            float al   = __expf(mold - mnew);   // first tile: exp(-inf)=0
            float ssum = 0.0f;
#pragma unroll 8
            for (int j = 0; j < 64; j++) {
                float p = __expf(Ps[t][j] - mnew);
                Ps[t][j] = p;
                ssum += p;
            }
            lrow[t] = lrow[t] * al + ssum;
            mrow[t] = mnew;
            arow[t] = al;
        }
        __syncthreads();

        // --- rescale + accumulate: O = O*alpha + P @ V ---
        float al[4];
#pragma unroll
        for (int i = 0; i < 4; i++) al[i] = arow[tm * 4 + i];
#pragma unroll
        for (int i = 0; i < 4; i++)
#pragma unroll
            for (int j = 0; j < 4; j++)
                acc[i][j] *= al[i];
#pragma unroll 4
        for (int kk = 0; kk < 64; kk++) {
            float4 vv = *(const float4*)&KVs[kk][tn * 4];
            const float vj[4] = {vv.x, vv.y, vv.z, vv.w};
            float pv[4];
#pragma unroll
            for (int i = 0; i < 4; i++) pv[i] = Ps[tm * 4 + i][kk];
#pragma unroll
            for (int i = 0; i < 4; i++)
#pragma unroll
                for (int j = 0; j < 4; j++)
                    acc[i][j] += pv[i] * vj[j];
        }
        __syncthreads();   // protect KVs/Ps before next tile's loads
    }

    // epilogue: divide by l, write [B][S][E]
    const int b = bh >> 3, h = bh & 7;
#pragma unroll
    for (int i = 0; i < 4; i++) {
        const int row = tm * 4 + i;
        const float inv = 1.0f / lrow[row];
        size_t base = ((size_t)b * Ss + s0 + row) * Ee + h * Hd + tn * 4;
#pragma unroll
        for (int j = 0; j < 4; j++)
            attn_out[base + j] = acc[i][j] * inv;
    }
}

// ---------------------------------------------------------------------------
// K3: output projection + bias + residual.
// attn: [B][S][E] row-major; Wo: [E][E]; y written TRANSPOSED as [B][E][S]
// so GroupNorm reads contiguous slabs.  y = (attn@Wo + bo)^T + x
// ---------------------------------------------------------------------------
__global__ __launch_bounds__(256) void outproj_kernel(
    const float* __restrict__ attn, const float* __restrict__ Wo,
    const float* __restrict__ bo, const float* __restrict__ xin,
    float* __restrict__ y)
{
    const int b  = blockIdx.z;
    const int e0 = blockIdx.y * 64;
    const int s0 = blockIdx.x * 64;
    const float* A = attn + (size_t)b * Ss * Ee;

    __shared__ float As[16][68];   // [k][m], transposed on store, padded
    __shared__ float Ws[16][64];

    const int t  = threadIdx.x;
    const int tm = t & 15, tn = t >> 4;
    float acc[4][4] = {};

    for (int k0 = 0; k0 < Ee; k0 += 16) {
        {   // A is [M][K] row-major: float4 along K, transpose into LDS
            const int m = t >> 2, kq = t & 3;
            float4 a4 = *(const float4*)&A[(size_t)(s0 + m) * Ee + k0 + kq * 4];
            As[kq * 4 + 0][m] = a4.x;
            As[kq * 4 + 1][m] = a4.y;
            As[kq * 4 + 2][m] = a4.z;
            As[kq * 4 + 3][m] = a4.w;
        }
#pragma unroll
        for (int i = 0; i < 4; i++) {
            int idx = t + i * 256;
            int c = idx >> 6, e = idx & 63;
            Ws[c][e] = Wo[(size_t)(k0 + c) * Ee + e0 + e];
        }
        __syncthreads();
#pragma unroll
        for (int c = 0; c < 16; c++) {
            const float4 a4 = *(const float4*)&As[c][tm * 4];
            const float4 w4 = *(const float4*)&Ws[c][tn * 4];
            const float av[4] = {a4.x, a4.y, a4.z, a4.w};
            const float wv[4] = {w4.x, w4.y, w4.z, w4.w};
#pragma unroll
            for (int i = 0; i < 4; i++)
#pragma unroll
                for (int j = 0; j < 4; j++)
                    acc[i][j] += av[i] * wv[j];
        }
        __syncthreads();
    }

#pragma unroll
    for (int j = 0; j < 4; j++) {
        const int e = e0 + tn * 4 + j;
        const float bb = bo[e];
        size_t ybase = ((size_t)b * Ee + e) * Ss + s0 + tm * 4;
        size_t xbase = ((size_t)b * Cc + e) * Ss + s0 + tm * 4;
#pragma unroll
        for (int i = 0; i < 4; i++)
            y[ybase + i] = acc[i][j] + bb + xin[xbase + i];
    }
}

// ---------------------------------------------------------------------------
// K4: GroupNorm.  y: [B][E][S]; one block per (b, group); each group's
// 16*1024 floats are contiguous.  out: [B][E][S] = d_out layout.
// ---------------------------------------------------------------------------
__global__ __launch_bounds__(256) void gnorm_kernel(
    const float* __restrict__ y, const float* __restrict__ gamma,
    const float* __restrict__ beta, float* __restrict__ out)
{
    const int bg = blockIdx.x;
    const int b = bg >> 5, g = bg & 31;
    const size_t base = ((size_t)b * Ee + g * Cpg) * Ss;
    const float4* y4 = (const float4*)(y + base);
    constexpr int N4 = (Cpg * Ss) / 4;   // 4096 float4s

    float s = 0.f, s2 = 0.f;
    for (int i = threadIdx.x; i < N4; i += 256) {
        float4 vv = y4[i];
        s  += vv.x + vv.y + vv.z + vv.w;
        s2 += vv.x * vv.x + vv.y * vv.y + vv.z * vv.z + vv.w * vv.w;
    }
#pragma unroll
    for (int off = 32; off > 0; off >>= 1) {
        s  += __shfl_down(s, off, 64);
        s2 += __shfl_down(s2, off, 64);
    }
    __shared__ float red[8];
    __shared__ float stats[2];
    const int lane = threadIdx.x & 63, wid = threadIdx.x >> 6;
    if (lane == 0) { red[wid] = s; red[4 + wid] = s2; }
    __syncthreads();
    if (threadIdx.x == 0) {
        float ts  = red[0] + red[1] + red[2] + red[3];
        float ts2 = red[4] + red[5] + red[6] + red[7];
        float mean = ts / (float)(Cpg * Ss);
        float var  = ts2 / (float)(Cpg * Ss) - mean * mean;
        stats[0] = mean;
        stats[1] = rsqrtf(var + 1e-5f);
    }
    __syncthreads();
    const float mean = stats[0], rstd = stats[1];
    float4* o4 = (float4*)(out + base);
    for (int i = threadIdx.x; i < N4; i += 256) {
        float4 vv = y4[i];
        const int c = g * Cpg + (i >> 8);   // 256 float4 per channel
        const float gm = gamma[c] * rstd;
        const float bt = beta[c];
        float4 r;
        r.x = (vv.x - mean) * gm + bt;
        r.y = (vv.y - mean) * gm + bt;
        r.z = (vv.z - mean) * gm + bt;
        r.w = (vv.w - mean) * gm + bt;
        o4[i] = r;
    }
}

// ---------------------------------------------------------------------------
extern "C" void kernel_launch(void* const* d_in, const int* in_sizes, int n_in,
                              void* d_out, int out_size, void* d_ws, size_t ws_size,
                              hipStream_t stream)
{
    const float* x     = (const float*)d_in[0];
    const float* Wq    = (const float*)d_in[1];
    const float* bq    = (const float*)d_in[2];
    const float* Wk    = (const float*)d_in[3];
    const float* bk    = (const float*)d_in[4];
    const float* Wv    = (const float*)d_in[5];
    const float* bv    = (const float*)d_in[6];
    const float* Wo    = (const float*)d_in[7];
    const float* bo    = (const float*)d_in[8];
    const float* gamma = (const float*)d_in[9];
    const float* beta  = (const float*)d_in[10];
    float* out = (float*)d_out;

    // workspace layout (floats): q | k | v | attn ; y reuses q's region
    const size_t QKV = (size_t)Bn * nHd * Ss * Hd;   // 4,194,304 floats (16 MB)
    float* ws    = (float*)d_ws;
    float* qb    = ws;
    float* kb    = ws + QKV;
    float* vb    = ws + 2 * QKV;
    float* attnb = ws + 3 * QKV;
    float* yb    = qb;   // q is dead after attn_kernel

    dim3 gGemm(Ss / 64, Ee / 64, Bn);       // (16, 8, 8)
    qkv_kernel<<<gGemm, 256, 0, stream>>>(x, Wq, bq, qb);
    qkv_kernel<<<gGemm, 256, 0, stream>>>(x, Wk, bk, kb);
    qkv_kernel<<<gGemm, 256, 0, stream>>>(x, Wv, bv, vb);

    attn_kernel<<<dim3(Ss / 64, Bn * nHd), 256, 0, stream>>>(qb, kb, vb, attnb);

    outproj_kernel<<<gGemm, 256, 0, stream>>>(attnb, Wo, bo, x, yb);

    gnorm_kernel<<<Bn * Gg, 256, 0, stream>>>(yb, gamma, beta, out);
}

// Round 2
// 203.334 us; speedup vs baseline: 4.1854x; 4.1854x over previous
//
#include <hip/hip_runtime.h>
#include <math.h>

constexpr int Bn  = 8;
constexpr int Cc  = 512;
constexpr int Ss  = 1024;   // H*W
constexpr int Ee  = 512;
constexpr int nHd = 8;
constexpr int Hd  = 64;
constexpr int Gg  = 32;
constexpr int Cpg = 16;

typedef __bf16 bf16x8 __attribute__((ext_vector_type(8)));
typedef float  f32x4  __attribute__((ext_vector_type(4)));

__device__ inline __bf16 cvt_bf16(float f) {
    unsigned u = __builtin_bit_cast(unsigned, f);
    u += 0x7fffu + ((u >> 16) & 1u);          // RTNE (finite values)
    unsigned short h = (unsigned short)(u >> 16);
    return __builtin_bit_cast(__bf16, h);
}

__device__ inline void gld16(const __bf16* g, __bf16* l) {
    __builtin_amdgcn_global_load_lds(
        (const __attribute__((address_space(1))) void*)g,
        (__attribute__((address_space(3))) void*)l, 16, 0, 0);
}

// ---------------------------------------------------------------------------
// Pre-pass 1: x[b][c][s] fp32 -> xt[b][s][c] bf16
// ---------------------------------------------------------------------------
__global__ __launch_bounds__(256) void transpose_x(
    const float* __restrict__ x, __bf16* __restrict__ xt)
{
    const int b = blockIdx.z, c0 = blockIdx.y * 32, s0 = blockIdx.x * 32;
    __shared__ float T[32][33];
    const int r8 = threadIdx.x >> 5, c32 = threadIdx.x & 31;
#pragma unroll
    for (int i = 0; i < 4; i++)
        T[r8 + i * 8][c32] = x[((size_t)b * Cc + c0 + r8 + i * 8) * Ss + s0 + c32];
    __syncthreads();
#pragma unroll
    for (int i = 0; i < 4; i++)
        xt[((size_t)b * Ss + s0 + r8 + i * 8) * Cc + c0 + c32] =
            cvt_bf16(T[c32][r8 + i * 8]);
}

// ---------------------------------------------------------------------------
// Pre-pass 2: W[c][e] fp32 -> Wt[e][c] bf16  (4 weights via blockIdx.z)
// ---------------------------------------------------------------------------
__global__ __launch_bounds__(256) void transpose_w(
    const float* __restrict__ w0, const float* __restrict__ w1,
    const float* __restrict__ w2, const float* __restrict__ w3,
    __bf16* __restrict__ d0, __bf16* __restrict__ d1,
    __bf16* __restrict__ d2, __bf16* __restrict__ d3)
{
    const int m = blockIdx.z;
    const float* src = (m == 0) ? w0 : (m == 1) ? w1 : (m == 2) ? w2 : w3;
    __bf16* dst = (m == 0) ? d0 : (m == 1) ? d1 : (m == 2) ? d2 : d3;
    const int e0 = blockIdx.x * 32, c0 = blockIdx.y * 32;
    __shared__ float T[32][33];
    const int r8 = threadIdx.x >> 5, c32 = threadIdx.x & 31;
#pragma unroll
    for (int i = 0; i < 4; i++)
        T[r8 + i * 8][c32] = src[(size_t)(c0 + r8 + i * 8) * Ee + e0 + c32];
    __syncthreads();
#pragma unroll
    for (int i = 0; i < 4; i++)
        dst[(size_t)(e0 + r8 + i * 8) * Cc + c0 + c32] = cvt_bf16(T[c32][r8 + i * 8]);
}

// ---------------------------------------------------------------------------
// K1: fused QKV MFMA GEMM.  out[s][e] = xt[s][:] . Wt[e][:] + bias[e]
// 128x128 tile, BK=32, 4 waves in 2x2, 16x16x32 mfma.
// Output bf16 [b][h][s][d] (e = h*64+d).
// ---------------------------------------------------------------------------
__global__ __launch_bounds__(256) void qkv_mfma(
    const __bf16* __restrict__ xt,
    const __bf16* __restrict__ wqt, const __bf16* __restrict__ wkt,
    const __bf16* __restrict__ wvt,
    const float* __restrict__ bq, const float* __restrict__ bk,
    const float* __restrict__ bv,
    __bf16* __restrict__ qb, __bf16* __restrict__ kb, __bf16* __restrict__ vb)
{
    const int b = blockIdx.z;
    const int wsel = blockIdx.y >> 2;
    const int e0 = (blockIdx.y & 3) * 128;
    const int s0 = blockIdx.x * 128;
    const __bf16* A  = xt + (size_t)b * Ss * Cc;
    const __bf16* Bm = (wsel == 0) ? wqt : (wsel == 1) ? wkt : wvt;
    const float*  bias = (wsel == 0) ? bq : (wsel == 1) ? bk : bv;
    __bf16* outp = (wsel == 0) ? qb : (wsel == 1) ? kb : vb;

    __shared__ __align__(16) __bf16 As[128 * 32];
    __shared__ __align__(16) __bf16 Bs[128 * 32];

    const int wave = threadIdx.x >> 6, lane = threadIdx.x & 63;
    const int lid = lane & 15, quad = lane >> 4;
    const int wm = wave & 1, wn = wave >> 1;
    const int srow = lane >> 2, sch = lane & 3;   // staging: 16 rows x 4 chunks

    f32x4 acc[4][4] = {};

    for (int k0 = 0; k0 < Cc; k0 += 32) {
#pragma unroll
        for (int i = 0; i < 2; i++) {
            const int inst = wave * 2 + i;        // 0..7, 16 rows each
            const int r = inst * 16 + srow;
            gld16(&A [(size_t)(s0 + r) * Cc + k0 + sch * 8], &As[inst * 512]);
            gld16(&Bm[(size_t)(e0 + r) * Cc + k0 + sch * 8], &Bs[inst * 512]);
        }
        __syncthreads();
        bf16x8 af[4], bf[4];
#pragma unroll
        for (int i = 0; i < 4; i++)
            af[i] = *(const bf16x8*)&As[(wm * 64 + i * 16 + lid) * 32 + quad * 8];
#pragma unroll
        for (int j = 0; j < 4; j++)
            bf[j] = *(const bf16x8*)&Bs[(wn * 64 + j * 16 + lid) * 32 + quad * 8];
#pragma unroll
        for (int i = 0; i < 4; i++)
#pragma unroll
            for (int j = 0; j < 4; j++)
                acc[i][j] = __builtin_amdgcn_mfma_f32_16x16x32_bf16(
                    af[i], bf[j], acc[i][j], 0, 0, 0);
        __syncthreads();
    }

    float bj[4];
#pragma unroll
    for (int j = 0; j < 4; j++) bj[j] = bias[e0 + wn * 64 + j * 16 + lid];

#pragma unroll
    for (int i = 0; i < 4; i++) {
#pragma unroll
        for (int j = 0; j < 4; j++) {
            const int e1 = e0 + wn * 64 + j * 16 + lid;
            const int h = e1 >> 6, d = e1 & 63;
#pragma unroll
            for (int r = 0; r < 4; r++) {
                const int s1 = s0 + wm * 64 + i * 16 + quad * 4 + r;
                outp[(((size_t)b * nHd + h) * Ss + s1) * Hd + d] =
                    cvt_bf16(acc[i][j][r] + bj[j]);
            }
        }
    }
}

// ---------------------------------------------------------------------------
// K2: MFMA flash attention.  q,k,v bf16 [bh][S][64]. One block = (bh, 64 q-rows),
// 4 waves each owning 16 q-rows. Online softmax in registers.
// Output bf16 attn[b][s][e] (e = h*64+d).
// ---------------------------------------------------------------------------
__global__ __launch_bounds__(256) void attn_mfma(
    const __bf16* __restrict__ q, const __bf16* __restrict__ k,
    const __bf16* __restrict__ v, __bf16* __restrict__ attn_out)
{
    const int bh = blockIdx.y;
    const int s0 = blockIdx.x * 64;
    const __bf16* qp = q + (size_t)bh * Ss * Hd;
    const __bf16* kp = k + (size_t)bh * Ss * Hd;
    const __bf16* vp = v + (size_t)bh * Ss * Hd;

    __shared__ __align__(16) __bf16 Ks[64 * 64];   // [sk][d], chunk-swizzled
    __shared__ __align__(16) __bf16 Vs[64 * 72];   // [d][sk], +8 pad (144B rows)
    __shared__ __align__(16) __bf16 Ps[64 * 72];   // [sq][sk], +8 pad

    const int wave = threadIdx.x >> 6, lane = threadIdx.x & 63;
    const int lid = lane & 15, quad = lane >> 4;

    // Q fragments: rows s0 + wave*16 + lid, reused for all 16 k-tiles
    bf16x8 qf[2];
#pragma unroll
    for (int kk = 0; kk < 2; kk++)
        qf[kk] = *(const bf16x8*)&qp[(size_t)(s0 + wave * 16 + lid) * Hd +
                                     kk * 32 + quad * 8];

    f32x4 acc[4] = {};                      // PV accum, n-tiles over d
    float mrow[4] = {-INFINITY, -INFINITY, -INFINITY, -INFINITY};
    float lrow[4] = {};
    const float cexp = 0.125f * 1.44269504f;   // scale * log2(e)

    for (int kt = 0; kt < 16; kt++) {
        const __bf16* kbase = kp + (size_t)kt * 64 * Hd;
        const __bf16* vbase = vp + (size_t)kt * 64 * Hd;

        // stage K via global_load_lds, XOR-swizzled 16B chunks
#pragma unroll
        for (int i = 0; i < 2; i++) {
            const int inst = wave * 2 + i;           // 8 rows x 128B each
            const int row = inst * 8 + (lane >> 3);
            const int ch  = lane & 7;
            gld16(&kbase[(size_t)row * Hd + ((ch ^ (row & 7)) * 8)],
                  &Ks[inst * 512]);
        }
        // stage V transposed: Vs[d][sk]
#pragma unroll
        for (int p = 0; p < 2; p++) {
            const int sk = p * 32 + (threadIdx.x & 31);
            const int d0 = (threadIdx.x >> 5) * 8;
            bf16x8 vv = *(const bf16x8*)&vbase[(size_t)sk * Hd + d0];
#pragma unroll
            for (int j = 0; j < 8; j++) Vs[(d0 + j) * 72 + sk] = vv[j];
        }
        __syncthreads();

        // scores: 4 sk-tiles x 2 k-steps
        f32x4 sc[4] = {};
#pragma unroll
        for (int nt = 0; nt < 4; nt++) {
            const int skr = nt * 16 + lid;
#pragma unroll
            for (int kk = 0; kk < 2; kk++) {
                const int cd = kk * 4 + quad;
                bf16x8 kf = *(const bf16x8*)&Ks[skr * 64 + ((cd ^ (skr & 7)) * 8)];
                sc[nt] = __builtin_amdgcn_mfma_f32_16x16x32_bf16(
                    qf[kk], kf, sc[nt], 0, 0, 0);
            }
        }

        // online softmax (rows = quad*4 + r, per-lane registers)
        float mx[4];
#pragma unroll
        for (int r = 0; r < 4; r++)
            mx[r] = fmaxf(fmaxf(sc[0][r], sc[1][r]), fmaxf(sc[2][r], sc[3][r]));
#pragma unroll
        for (int off = 1; off < 16; off <<= 1)
#pragma unroll
            for (int r = 0; r < 4; r++)
                mx[r] = fmaxf(mx[r], __shfl_xor(mx[r], off, 64));

        float alpha[4];
#pragma unroll
        for (int r = 0; r < 4; r++) {
            const float mnew = fmaxf(mrow[r], mx[r]);
            alpha[r] = exp2f((mrow[r] - mnew) * cexp);
            mrow[r] = mnew;
        }
        float rs[4] = {};
#pragma unroll
        for (int nt = 0; nt < 4; nt++)
#pragma unroll
            for (int r = 0; r < 4; r++) {
                const float p = exp2f((sc[nt][r] - mrow[r]) * cexp);
                rs[r] += p;
                Ps[(wave * 16 + quad * 4 + r) * 72 + nt * 16 + lid] = cvt_bf16(p);
            }
#pragma unroll
        for (int off = 1; off < 16; off <<= 1)
#pragma unroll
            for (int r = 0; r < 4; r++) rs[r] += __shfl_xor(rs[r], off, 64);
#pragma unroll
        for (int r = 0; r < 4; r++) lrow[r] = lrow[r] * alpha[r] + rs[r];
#pragma unroll
        for (int nt = 0; nt < 4; nt++)
#pragma unroll
            for (int r = 0; r < 4; r++) acc[nt][r] *= alpha[r];

        // PV: A = P (own wave's rows), B = V^T from Vs
#pragma unroll
        for (int kk = 0; kk < 2; kk++) {
            bf16x8 pf = *(const bf16x8*)&Ps[(wave * 16 + lid) * 72 +
                                            kk * 32 + quad * 8];
#pragma unroll
            for (int nt = 0; nt < 4; nt++) {
                bf16x8 vf = *(const bf16x8*)&Vs[(nt * 16 + lid) * 72 +
                                                kk * 32 + quad * 8];
                acc[nt] = __builtin_amdgcn_mfma_f32_16x16x32_bf16(
                    pf, vf, acc[nt], 0, 0, 0);
            }
        }
        __syncthreads();   // all waves done with Ks/Vs before restage
    }

    const int b = bh >> 3, h = bh & 7;
#pragma unroll
    for (int r = 0; r < 4; r++) {
        const int row = s0 + wave * 16 + quad * 4 + r;
        const float inv = 1.0f / lrow[r];
#pragma unroll
        for (int nt = 0; nt < 4; nt++)
            attn_out[((size_t)b * Ss + row) * Ee + h * Hd + nt * 16 + lid] =
                cvt_bf16(acc[nt][r] * inv);
    }
}

// ---------------------------------------------------------------------------
// K3: output projection, M=eo N=s K=ei so y[b][eo][s] stores coalesce.
// y = Wo^T-GEMM + bo + residual, fp32 out for GroupNorm.
// ---------------------------------------------------------------------------
__global__ __launch_bounds__(256) void outproj_mfma(
    const __bf16* __restrict__ attnb, const __bf16* __restrict__ wot,
    const float* __restrict__ bo, const float* __restrict__ xin,
    float* __restrict__ y)
{
    const int b  = blockIdx.z;
    const int e0 = blockIdx.y * 128;   // eo
    const int s0 = blockIdx.x * 128;
    const __bf16* Bm = attnb + (size_t)b * Ss * Ee;   // [s][ei]

    __shared__ __align__(16) __bf16 As[128 * 32];     // Wot rows (eo)
    __shared__ __align__(16) __bf16 Bs[128 * 32];     // attn rows (s)

    const int wave = threadIdx.x >> 6, lane = threadIdx.x & 63;
    const int lid = lane & 15, quad = lane >> 4;
    const int wm = wave & 1, wn = wave >> 1;
    const int srow = lane >> 2, sch = lane & 3;

    f32x4 acc[4][4] = {};

    for (int k0 = 0; k0 < Ee; k0 += 32) {
#pragma unroll
        for (int i = 0; i < 2; i++) {
            const int inst = wave * 2 + i;
            const int r = inst * 16 + srow;
            gld16(&wot[(size_t)(e0 + r) * Ee + k0 + sch * 8], &As[inst * 512]);
            gld16(&Bm [(size_t)(s0 + r) * Ee + k0 + sch * 8], &Bs[inst * 512]);
        }
        __syncthreads();
        bf16x8 af[4], bf[4];
#pragma unroll
        for (int i = 0; i < 4; i++)
            af[i] = *(const bf16x8*)&As[(wm * 64 + i * 16 + lid) * 32 + quad * 8];
#pragma unroll
        for (int j = 0; j < 4; j++)
            bf[j] = *(const bf16x8*)&Bs[(wn * 64 + j * 16 + lid) * 32 + quad * 8];
#pragma unroll
        for (int i = 0; i < 4; i++)
#pragma unroll
            for (int j = 0; j < 4; j++)
                acc[i][j] = __builtin_amdgcn_mfma_f32_16x16x32_bf16(
                    af[i], bf[j], acc[i][j], 0, 0, 0);
        __syncthreads();
    }

#pragma unroll
    for (int i = 0; i < 4; i++) {
#pragma unroll
        for (int r = 0; r < 4; r++) {
            const int eo1 = e0 + wm * 64 + i * 16 + quad * 4 + r;
            const float bb = bo[eo1];
#pragma unroll
            for (int j = 0; j < 4; j++) {
                const int s1 = s0 + wn * 64 + j * 16 + lid;
                const size_t idx = ((size_t)b * Ee + eo1) * Ss + s1;
                y[idx] = acc[i][j][r] + bb + xin[idx];
            }
        }
    }
}

// ---------------------------------------------------------------------------
// K4: GroupNorm (unchanged from R1).  y fp32 [B][E][S], contiguous per group.
// ---------------------------------------------------------------------------
__global__ __launch_bounds__(256) void gnorm_kernel(
    const float* __restrict__ y, const float* __restrict__ gamma,
    const float* __restrict__ beta, float* __restrict__ out)
{
    const int bg = blockIdx.x;
    const int b = bg >> 5, g = bg & 31;
    const size_t base = ((size_t)b * Ee + g * Cpg) * Ss;
    const float4* y4 = (const float4*)(y + base);
    constexpr int N4 = (Cpg * Ss) / 4;

    float s = 0.f, s2 = 0.f;
    for (int i = threadIdx.x; i < N4; i += 256) {
        float4 vv = y4[i];
        s  += vv.x + vv.y + vv.z + vv.w;
        s2 += vv.x * vv.x + vv.y * vv.y + vv.z * vv.z + vv.w * vv.w;
    }
#pragma unroll
    for (int off = 32; off > 0; off >>= 1) {
        s  += __shfl_down(s, off, 64);
        s2 += __shfl_down(s2, off, 64);
    }
    __shared__ float red[8];
    __shared__ float stats[2];
    const int lane = threadIdx.x & 63, wid = threadIdx.x >> 6;
    if (lane == 0) { red[wid] = s; red[4 + wid] = s2; }
    __syncthreads();
    if (threadIdx.x == 0) {
        float ts  = red[0] + red[1] + red[2] + red[3];
        float ts2 = red[4] + red[5] + red[6] + red[7];
        float mean = ts / (float)(Cpg * Ss);
        float var  = ts2 / (float)(Cpg * Ss) - mean * mean;
        stats[0] = mean;
        stats[1] = rsqrtf(var + 1e-5f);
    }
    __syncthreads();
    const float mean = stats[0], rstd = stats[1];
    float4* o4 = (float4*)(out + base);
    for (int i = threadIdx.x; i < N4; i += 256) {
        float4 vv = y4[i];
        const int c = g * Cpg + (i >> 8);
        const float gm = gamma[c] * rstd;
        const float bt = beta[c];
        float4 r;
        r.x = (vv.x - mean) * gm + bt;
        r.y = (vv.y - mean) * gm + bt;
        r.z = (vv.z - mean) * gm + bt;
        r.w = (vv.w - mean) * gm + bt;
        o4[i] = r;
    }
}

// ---------------------------------------------------------------------------
extern "C" void kernel_launch(void* const* d_in, const int* in_sizes, int n_in,
                              void* d_out, int out_size, void* d_ws, size_t ws_size,
                              hipStream_t stream)
{
    const float* x     = (const float*)d_in[0];
    const float* Wq    = (const float*)d_in[1];
    const float* bq    = (const float*)d_in[2];
    const float* Wk    = (const float*)d_in[3];
    const float* bk    = (const float*)d_in[4];
    const float* Wv    = (const float*)d_in[5];
    const float* bv    = (const float*)d_in[6];
    const float* Wo    = (const float*)d_in[7];
    const float* bo    = (const float*)d_in[8];
    const float* gamma = (const float*)d_in[9];
    const float* beta  = (const float*)d_in[10];
    float* out = (float*)d_out;

    // workspace layout (bytes)
    char* ws = (char*)d_ws;
    __bf16* xt    = (__bf16*)ws;                          //  8 MiB
    __bf16* wqt   = (__bf16*)(ws + (8u << 20));           // 512 KiB
    __bf16* wkt   = (__bf16*)(ws + (8u << 20) + (512u << 10));
    __bf16* wvt   = (__bf16*)(ws + (9u << 20));
    __bf16* wot   = (__bf16*)(ws + (9u << 20) + (512u << 10));
    __bf16* qb    = (__bf16*)(ws + (10u << 20));          //  8 MiB
    __bf16* kb    = (__bf16*)(ws + (18u << 20));          //  8 MiB
    __bf16* vb    = (__bf16*)(ws + (26u << 20));          //  8 MiB
    __bf16* attnb = (__bf16*)(ws + (34u << 20));          //  8 MiB
    float*  yb    = (float*) (ws + (42u << 20));          // 16 MiB

    transpose_x<<<dim3(Ss / 32, Cc / 32, Bn), 256, 0, stream>>>(x, xt);
    transpose_w<<<dim3(Ee / 32, Cc / 32, 4), 256, 0, stream>>>(
        Wq, Wk, Wv, Wo, wqt, wkt, wvt, wot);

    qkv_mfma<<<dim3(Ss / 128, 12, Bn), 256, 0, stream>>>(
        xt, wqt, wkt, wvt, bq, bk, bv, qb, kb, vb);

    attn_mfma<<<dim3(Ss / 64, Bn * nHd), 256, 0, stream>>>(qb, kb, vb, attnb);

    outproj_mfma<<<dim3(Ss / 128, Ee / 128, Bn), 256, 0, stream>>>(
        attnb, wot, bo, x, yb);

    gnorm_kernel<<<Bn * Gg, 256, 0, stream>>>(yb, gamma, beta, out);
}

// Round 3
// 168.355 us; speedup vs baseline: 5.0550x; 1.2078x over previous
//
#include <hip/hip_runtime.h>
#include <math.h>

constexpr int Bn  = 8;
constexpr int Cc  = 512;
constexpr int Ss  = 1024;   // H*W
constexpr int Ee  = 512;
constexpr int nHd = 8;
constexpr int Hd  = 64;
constexpr int Gg  = 32;
constexpr int Cpg = 16;

typedef __bf16 bf16x8 __attribute__((ext_vector_type(8)));
typedef float  f32x4  __attribute__((ext_vector_type(4)));
typedef float  f32x16 __attribute__((ext_vector_type(16)));

__device__ inline __bf16 cvt_bf16(float f) {
    unsigned u = __builtin_bit_cast(unsigned, f);
    u += 0x7fffu + ((u >> 16) & 1u);          // RTNE (finite values)
    unsigned short h = (unsigned short)(u >> 16);
    return __builtin_bit_cast(__bf16, h);
}

__device__ inline void gld16(const __bf16* g, __bf16* l) {
    __builtin_amdgcn_global_load_lds(
        (const __attribute__((address_space(1))) void*)g,
        (__attribute__((address_space(3))) void*)l, 16, 0, 0);
}

// pack two fp32 -> 2 bf16 (RTZ) in one dword: low = lo, high = hi
__device__ inline unsigned pk_bf16_rtz(float hi, float lo) {
    return __builtin_amdgcn_perm(__builtin_bit_cast(unsigned, hi),
                                 __builtin_bit_cast(unsigned, lo), 0x07060302u);
}

// ---------------------------------------------------------------------------
// Pre-pass 1: x[b][c][s] fp32 -> xt[b][s][c] bf16
// ---------------------------------------------------------------------------
__global__ __launch_bounds__(256) void transpose_x(
    const float* __restrict__ x, __bf16* __restrict__ xt)
{
    const int b = blockIdx.z, c0 = blockIdx.y * 32, s0 = blockIdx.x * 32;
    __shared__ float T[32][33];
    const int r8 = threadIdx.x >> 5, c32 = threadIdx.x & 31;
#pragma unroll
    for (int i = 0; i < 4; i++)
        T[r8 + i * 8][c32] = x[((size_t)b * Cc + c0 + r8 + i * 8) * Ss + s0 + c32];
    __syncthreads();
#pragma unroll
    for (int i = 0; i < 4; i++)
        xt[((size_t)b * Ss + s0 + r8 + i * 8) * Cc + c0 + c32] =
            cvt_bf16(T[c32][r8 + i * 8]);
}

// ---------------------------------------------------------------------------
// Pre-pass 2: W[c][e] fp32 -> Wt[e][c] bf16  (4 weights via blockIdx.z)
// ---------------------------------------------------------------------------
__global__ __launch_bounds__(256) void transpose_w(
    const float* __restrict__ w0, const float* __restrict__ w1,
    const float* __restrict__ w2, const float* __restrict__ w3,
    __bf16* __restrict__ d0, __bf16* __restrict__ d1,
    __bf16* __restrict__ d2, __bf16* __restrict__ d3)
{
    const int m = blockIdx.z;
    const float* src = (m == 0) ? w0 : (m == 1) ? w1 : (m == 2) ? w2 : w3;
    __bf16* dst = (m == 0) ? d0 : (m == 1) ? d1 : (m == 2) ? d2 : d3;
    const int e0 = blockIdx.x * 32, c0 = blockIdx.y * 32;
    __shared__ float T[32][33];
    const int r8 = threadIdx.x >> 5, c32 = threadIdx.x & 31;
#pragma unroll
    for (int i = 0; i < 4; i++)
        T[r8 + i * 8][c32] = src[(size_t)(c0 + r8 + i * 8) * Ee + e0 + c32];
    __syncthreads();
#pragma unroll
    for (int i = 0; i < 4; i++)
        dst[(size_t)(e0 + r8 + i * 8) * Cc + c0 + c32] = cvt_bf16(T[c32][r8 + i * 8]);
}

// ---------------------------------------------------------------------------
// K1: fused QKV MFMA GEMM.  out[s][e] = xt[s][:] . Wt[e][:] + bias[e]
// Q,K -> [b][h][s][d] bf16 (scalar stores, 32B segments).
// V   -> vt[b][h][d][S] bf16 via LDS-transpose epilogue (coalesced 16B).
// ---------------------------------------------------------------------------
__global__ __launch_bounds__(256) void qkv_mfma(
    const __bf16* __restrict__ xt,
    const __bf16* __restrict__ wqt, const __bf16* __restrict__ wkt,
    const __bf16* __restrict__ wvt,
    const float* __restrict__ bq, const float* __restrict__ bk,
    const float* __restrict__ bv,
    __bf16* __restrict__ qb, __bf16* __restrict__ kb, __bf16* __restrict__ vt)
{
    const int b = blockIdx.z;
    const int wsel = blockIdx.y >> 2;
    const int e0 = (blockIdx.y & 3) * 128;
    const int s0 = blockIdx.x * 128;
    const __bf16* A  = xt + (size_t)b * Ss * Cc;
    const __bf16* Bm = (wsel == 0) ? wqt : (wsel == 1) ? wkt : wvt;
    const float*  bias = (wsel == 0) ? bq : (wsel == 1) ? bk : bv;

    __shared__ __align__(16) __bf16 As[128 * 32];
    __shared__ __align__(16) __bf16 Bs[128 * 32];
    __shared__ __align__(16) __bf16 T[128 * 136];   // V epilogue transpose

    const int wave = threadIdx.x >> 6, lane = threadIdx.x & 63;
    const int lid = lane & 15, quad = lane >> 4;
    const int wm = wave & 1, wn = wave >> 1;
    const int srow = lane >> 2, sch = lane & 3;   // staging: 16 rows x 4 chunks

    f32x4 acc[4][4] = {};

    for (int k0 = 0; k0 < Cc; k0 += 32) {
#pragma unroll
        for (int i = 0; i < 2; i++) {
            const int inst = wave * 2 + i;        // 0..7, 16 rows each
            const int r = inst * 16 + srow;
            gld16(&A [(size_t)(s0 + r) * Cc + k0 + sch * 8], &As[inst * 512]);
            gld16(&Bm[(size_t)(e0 + r) * Cc + k0 + sch * 8], &Bs[inst * 512]);
        }
        __syncthreads();
        bf16x8 af[4], bf[4];
#pragma unroll
        for (int i = 0; i < 4; i++)
            af[i] = *(const bf16x8*)&As[(wm * 64 + i * 16 + lid) * 32 + quad * 8];
#pragma unroll
        for (int j = 0; j < 4; j++)
            bf[j] = *(const bf16x8*)&Bs[(wn * 64 + j * 16 + lid) * 32 + quad * 8];
#pragma unroll
        for (int i = 0; i < 4; i++)
#pragma unroll
            for (int j = 0; j < 4; j++)
                acc[i][j] = __builtin_amdgcn_mfma_f32_16x16x32_bf16(
                    af[i], bf[j], acc[i][j], 0, 0, 0);
        __syncthreads();
    }

    float bj[4];
#pragma unroll
    for (int j = 0; j < 4; j++) bj[j] = bias[e0 + wn * 64 + j * 16 + lid];

    if (wsel == 2) {
        // V: transpose through LDS, emit vt[b][h][d][S] with 16B stores
#pragma unroll
        for (int i = 0; i < 4; i++) {
            const int s4 = wm * 64 + i * 16 + quad * 4;
#pragma unroll
            for (int j = 0; j < 4; j++) {
                const int e_l = wn * 64 + j * 16 + lid;
                unsigned short u0 = __builtin_bit_cast(unsigned short, cvt_bf16(acc[i][j][0] + bj[j]));
                unsigned short u1 = __builtin_bit_cast(unsigned short, cvt_bf16(acc[i][j][1] + bj[j]));
                unsigned short u2 = __builtin_bit_cast(unsigned short, cvt_bf16(acc[i][j][2] + bj[j]));
                unsigned short u3 = __builtin_bit_cast(unsigned short, cvt_bf16(acc[i][j][3] + bj[j]));
                uint2 pk;
                pk.x = (unsigned)u0 | ((unsigned)u1 << 16);
                pk.y = (unsigned)u2 | ((unsigned)u3 << 16);
                *(uint2*)&T[e_l * 136 + s4] = pk;
            }
        }
        __syncthreads();
        const int t = threadIdx.x;
#pragma unroll
        for (int it = 0; it < 8; it++) {
            const int idx = t + it * 256;
            const int e_l = idx >> 4, c8 = (idx & 15) * 8;
            bf16x8 val = *(const bf16x8*)&T[e_l * 136 + c8];
            const int e_g = e0 + e_l;
            const int head = e_g >> 6, d = e_g & 63;
            *(bf16x8*)&vt[(((size_t)b * nHd + head) * Hd + d) * Ss + s0 + c8] = val;
        }
    } else {
        __bf16* outp = (wsel == 0) ? qb : kb;
#pragma unroll
        for (int i = 0; i < 4; i++) {
#pragma unroll
            for (int j = 0; j < 4; j++) {
                const int e1 = e0 + wn * 64 + j * 16 + lid;
                const int head = e1 >> 6, d = e1 & 63;
#pragma unroll
                for (int r = 0; r < 4; r++) {
                    const int s1 = s0 + wm * 64 + i * 16 + quad * 4 + r;
                    outp[(((size_t)b * nHd + head) * Ss + s1) * Hd + d] =
                        cvt_bf16(acc[i][j][r] + bj[j]);
                }
            }
        }
    }
}

// ---------------------------------------------------------------------------
// K2: MFMA flash attention, S^T orientation, no-max softmax.
// q,k: [bh][S][64] bf16; vt: [bh][64][S] bf16.
// Block = 128 q-rows (4 waves x 32), iterates 16 tiles of 64 keys.
// Scores: S^T = K.Q^T (32x32x16 mfma) -> lane owns one q-row (col=lane&31).
// P row-sums accumulate in-register; single shfl at epilogue. P -> LDS as
// packed b64 (XOR-swizzled), PV: O = P.V with V^T rows from LDS.
// Output bf16 attn[b][s][e] (e = h*64+d).
// ---------------------------------------------------------------------------
__global__ __launch_bounds__(256, 2) void attn_mfma(
    const __bf16* __restrict__ q, const __bf16* __restrict__ k,
    const __bf16* __restrict__ vt, __bf16* __restrict__ attn_out)
{
    const int bh = blockIdx.x;          // bh-major grid: q-tiles of one bh
    const int s0 = blockIdx.y * 128;    // land on one XCD (stride 64 % 8 == 0)
    const __bf16* qp = q  + (size_t)bh * Ss * Hd;
    const __bf16* kp = k  + (size_t)bh * Ss * Hd;
    const __bf16* vp = vt + (size_t)bh * Hd * Ss;

    __shared__ __align__(16) __bf16 Ks[64 * 64];      // [sk][d], chunk-swizzled
    __shared__ __align__(16) __bf16 Vs[64 * 64];      // [d][sk], chunk-swizzled
    __shared__ __align__(16) __bf16 Ps[4][32 * 64];   // per-wave [sq][sk], swizzled

    const int wave = threadIdx.x >> 6, lane = threadIdx.x & 63;
    const int nl = lane & 31, h = lane >> 5;
    __bf16* PsW = Ps[wave];

    // Q fragments (B-operand = rows of Q), persistent across all k-tiles
    const int sq = s0 + wave * 32 + nl;
    bf16x8 qf[4];
#pragma unroll
    for (int kk2 = 0; kk2 < 4; kk2++)
        qf[kk2] = *(const bf16x8*)&qp[(size_t)sq * Hd + kk2 * 16 + h * 8];

    f32x16 oacc[2] = {};
    float rs = 0.0f;
    const float cexp = 0.125f * 1.44269504f;   // scale * log2(e)

    const int srow = lane >> 3, sch = lane & 7;
    for (int kt = 0; kt < 16; kt++) {
        // stage K tile [64 sk][64 d] and V^T tile [64 d][64 sk], XOR-swizzled
#pragma unroll
        for (int i = 0; i < 2; i++) {
            const int inst = wave * 2 + i;         // 0..7, 8 rows x 128B each
            const int rK = inst * 8 + srow;
            gld16(&kp[(size_t)(kt * 64 + rK) * Hd + ((sch ^ (rK & 7)) * 8)],
                  &Ks[inst * 512]);
            gld16(&vp[(size_t)rK * Ss + kt * 64 + ((sch ^ (rK & 7)) * 8)],
                  &Vs[inst * 512]);
        }
        __syncthreads();

        // scores: S^T[sk][sq], two 32-row sk tiles, K-dim = d (4 steps of 16)
        f32x16 sc[2] = {};
#pragma unroll
        for (int kk2 = 0; kk2 < 4; kk2++) {
#pragma unroll
            for (int mt = 0; mt < 2; mt++) {
                bf16x8 kf = *(const bf16x8*)&Ks[(mt * 32 + nl) * 64 +
                                                (((2 * kk2 + h) ^ (nl & 7)) * 8)];
                sc[mt] = __builtin_amdgcn_mfma_f32_32x32x16_bf16(
                    kf, qf[kk2], sc[mt], 0, 0, 0);
            }
        }

        // no-max softmax: p = exp2(s*c); in-lane row-sum; pack -> Ps
#pragma unroll
        for (int mt = 0; mt < 2; mt++) {
            float p[16];
#pragma unroll
            for (int r = 0; r < 16; r++) {
                p[r] = __builtin_amdgcn_exp2f(sc[mt][r] * cexp);
                rs += p[r];
            }
#pragma unroll
            for (int g = 0; g < 4; g++) {
                uint2 pk;
                pk.x = pk_bf16_rtz(p[4 * g + 1], p[4 * g + 0]);
                pk.y = pk_bf16_rtz(p[4 * g + 3], p[4 * g + 2]);
                const int ch = (2 * g + h + 8 * mt) ^ ((nl & 7) << 1);
                *(uint2*)&PsW[nl * 64 + ch * 4] = pk;
            }
        }
        // own-wave P round-trip: no barrier needed (compiler waits lgkmcnt)

        // PV: O[sq][d] = P[sq][sk] . V[sk][d], V^T rows from Vs
#pragma unroll
        for (int kk = 0; kk < 4; kk++) {
            const int cp = (4 * kk + 2 * h) ^ ((nl & 7) << 1);
            bf16x8 pf = *(const bf16x8*)&PsW[nl * 64 + cp * 4];
#pragma unroll
            for (int dt = 0; dt < 2; dt++) {
                bf16x8 vf = *(const bf16x8*)&Vs[(dt * 32 + nl) * 64 +
                                                (((2 * kk + h) ^ (nl & 7)) * 8)];
                oacc[dt] = __builtin_amdgcn_mfma_f32_32x32x16_bf16(
                    pf, vf, oacc[dt], 0, 0, 0);
            }
        }
        __syncthreads();   // Ks/Vs consumed before next stage
    }

    // epilogue: l = cross-half sum of rs; normalize; store [b][s][e]
    rs += __shfl_xor(rs, 32, 64);
    const float inv = 1.0f / rs;          // valid for sq = lane&31
    const int b = bh >> 3, head = bh & 7;
#pragma unroll
    for (int r = 0; r < 16; r++) {
        const int rowq = (r & 3) + 8 * (r >> 2) + 4 * h;   // local q-row of O
        const float invr = __shfl(inv, rowq, 64);
        const int s1 = s0 + wave * 32 + rowq;
#pragma unroll
        for (int dt = 0; dt < 2; dt++)
            attn_out[((size_t)b * Ss + s1) * Ee + head * Hd + dt * 32 + nl] =
                cvt_bf16(oacc[dt][r] * invr);
    }
}

// ---------------------------------------------------------------------------
// K3: output projection, M=eo N=s K=ei so y[b][eo][s] stores coalesce.
// y = Wo^T-GEMM + bo + residual, fp32 out for GroupNorm.
// ---------------------------------------------------------------------------
__global__ __launch_bounds__(256) void outproj_mfma(
    const __bf16* __restrict__ attnb, const __bf16* __restrict__ wot,
    const float* __restrict__ bo, const float* __restrict__ xin,
    float* __restrict__ y)
{
    const int b  = blockIdx.z;
    const int e0 = blockIdx.y * 128;   // eo
    const int s0 = blockIdx.x * 128;
    const __bf16* Bm = attnb + (size_t)b * Ss * Ee;   // [s][ei]

    __shared__ __align__(16) __bf16 As[128 * 32];     // Wot rows (eo)
    __shared__ __align__(16) __bf16 Bs[128 * 32];     // attn rows (s)

    const int wave = threadIdx.x >> 6, lane = threadIdx.x & 63;
    const int lid = lane & 15, quad = lane >> 4;
    const int wm = wave & 1, wn = wave >> 1;
    const int srow = lane >> 2, sch = lane & 3;

    f32x4 acc[4][4] = {};

    for (int k0 = 0; k0 < Ee; k0 += 32) {
#pragma unroll
        for (int i = 0; i < 2; i++) {
            const int inst = wave * 2 + i;
            const int r = inst * 16 + srow;
            gld16(&wot[(size_t)(e0 + r) * Ee + k0 + sch * 8], &As[inst * 512]);
            gld16(&Bm [(size_t)(s0 + r) * Ee + k0 + sch * 8], &Bs[inst * 512]);
        }
        __syncthreads();
        bf16x8 af[4], bf[4];
#pragma unroll
        for (int i = 0; i < 4; i++)
            af[i] = *(const bf16x8*)&As[(wm * 64 + i * 16 + lid) * 32 + quad * 8];
#pragma unroll
        for (int j = 0; j < 4; j++)
            bf[j] = *(const bf16x8*)&Bs[(wn * 64 + j * 16 + lid) * 32 + quad * 8];
#pragma unroll
        for (int i = 0; i < 4; i++)
#pragma unroll
            for (int j = 0; j < 4; j++)
                acc[i][j] = __builtin_amdgcn_mfma_f32_16x16x32_bf16(
                    af[i], bf[j], acc[i][j], 0, 0, 0);
        __syncthreads();
    }

#pragma unroll
    for (int i = 0; i < 4; i++) {
#pragma unroll
        for (int r = 0; r < 4; r++) {
            const int eo1 = e0 + wm * 64 + i * 16 + quad * 4 + r;
            const float bb = bo[eo1];
#pragma unroll
            for (int j = 0; j < 4; j++) {
                const int s1 = s0 + wn * 64 + j * 16 + lid;
                const size_t idx = ((size_t)b * Ee + eo1) * Ss + s1;
                y[idx] = acc[i][j][r] + bb + xin[idx];
            }
        }
    }
}

// ---------------------------------------------------------------------------
// K4: GroupNorm.  y fp32 [B][E][S], contiguous per group.
// ---------------------------------------------------------------------------
__global__ __launch_bounds__(256) void gnorm_kernel(
    const float* __restrict__ y, const float* __restrict__ gamma,
    const float* __restrict__ beta, float* __restrict__ out)
{
    const int bg = blockIdx.x;
    const int b = bg >> 5, g = bg & 31;
    const size_t base = ((size_t)b * Ee + g * Cpg) * Ss;
    const float4* y4 = (const float4*)(y + base);
    constexpr int N4 = (Cpg * Ss) / 4;

    float s = 0.f, s2 = 0.f;
    for (int i = threadIdx.x; i < N4; i += 256) {
        float4 vv = y4[i];
        s  += vv.x + vv.y + vv.z + vv.w;
        s2 += vv.x * vv.x + vv.y * vv.y + vv.z * vv.z + vv.w * vv.w;
    }
#pragma unroll
    for (int off = 32; off > 0; off >>= 1) {
        s  += __shfl_down(s, off, 64);
        s2 += __shfl_down(s2, off, 64);
    }
    __shared__ float red[8];
    __shared__ float stats[2];
    const int lane = threadIdx.x & 63, wid = threadIdx.x >> 6;
    if (lane == 0) { red[wid] = s; red[4 + wid] = s2; }
    __syncthreads();
    if (threadIdx.x == 0) {
        float ts  = red[0] + red[1] + red[2] + red[3];
        float ts2 = red[4] + red[5] + red[6] + red[7];
        float mean = ts / (float)(Cpg * Ss);
        float var  = ts2 / (float)(Cpg * Ss) - mean * mean;
        stats[0] = mean;
        stats[1] = rsqrtf(var + 1e-5f);
    }
    __syncthreads();
    const float mean = stats[0], rstd = stats[1];
    float4* o4 = (float4*)(out + base);
    for (int i = threadIdx.x; i < N4; i += 256) {
        float4 vv = y4[i];
        const int c = g * Cpg + (i >> 8);
        const float gm = gamma[c] * rstd;
        const float bt = beta[c];
        float4 r;
        r.x = (vv.x - mean) * gm + bt;
        r.y = (vv.y - mean) * gm + bt;
        r.z = (vv.z - mean) * gm + bt;
        r.w = (vv.w - mean) * gm + bt;
        o4[i] = r;
    }
}

// ---------------------------------------------------------------------------
extern "C" void kernel_launch(void* const* d_in, const int* in_sizes, int n_in,
                              void* d_out, int out_size, void* d_ws, size_t ws_size,
                              hipStream_t stream)
{
    const float* x     = (const float*)d_in[0];
    const float* Wq    = (const float*)d_in[1];
    const float* bq    = (const float*)d_in[2];
    const float* Wk    = (const float*)d_in[3];
    const float* bk    = (const float*)d_in[4];
    const float* Wv    = (const float*)d_in[5];
    const float* bv    = (const float*)d_in[6];
    const float* Wo    = (const float*)d_in[7];
    const float* bo    = (const float*)d_in[8];
    const float* gamma = (const float*)d_in[9];
    const float* beta  = (const float*)d_in[10];
    float* out = (float*)d_out;

    // workspace layout (bytes)
    char* ws = (char*)d_ws;
    __bf16* xt    = (__bf16*)ws;                          //  8 MiB
    __bf16* wqt   = (__bf16*)(ws + (8u << 20));           // 512 KiB
    __bf16* wkt   = (__bf16*)(ws + (8u << 20) + (512u << 10));
    __bf16* wvt   = (__bf16*)(ws + (9u << 20));
    __bf16* wot   = (__bf16*)(ws + (9u << 20) + (512u << 10));
    __bf16* qb    = (__bf16*)(ws + (10u << 20));          //  8 MiB
    __bf16* kb    = (__bf16*)(ws + (18u << 20));          //  8 MiB
    __bf16* vtb   = (__bf16*)(ws + (26u << 20));          //  8 MiB (V^T)
    __bf16* attnb = (__bf16*)(ws + (34u << 20));          //  8 MiB
    float*  yb    = (float*) (ws + (42u << 20));          // 32 MiB

    transpose_x<<<dim3(Ss / 32, Cc / 32, Bn), 256, 0, stream>>>(x, xt);
    transpose_w<<<dim3(Ee / 32, Cc / 32, 4), 256, 0, stream>>>(
        Wq, Wk, Wv, Wo, wqt, wkt, wvt, wot);

    qkv_mfma<<<dim3(Ss / 128, 12, Bn), 256, 0, stream>>>(
        xt, wqt, wkt, wvt, bq, bk, bv, qb, kb, vtb);

    attn_mfma<<<dim3(Bn * nHd, Ss / 128), 256, 0, stream>>>(qb, kb, vtb, attnb);

    outproj_mfma<<<dim3(Ss / 128, Ee / 128, Bn), 256, 0, stream>>>(
        attnb, wot, bo, x, yb);

    gnorm_kernel<<<Bn * Gg, 256, 0, stream>>>(yb, gamma, beta, out);
}

// Round 5
// 161.383 us; speedup vs baseline: 5.2734x; 1.0432x over previous
//
#include <hip/hip_runtime.h>
#include <math.h>

constexpr int Bn  = 8;
constexpr int Cc  = 512;
constexpr int Ss  = 1024;   // H*W
constexpr int Ee  = 512;
constexpr int nHd = 8;
constexpr int Hd  = 64;
constexpr int Gg  = 32;
constexpr int Cpg = 16;

typedef __bf16 bf16x8 __attribute__((ext_vector_type(8)));
typedef float  f32x4  __attribute__((ext_vector_type(4)));
typedef float  f32x16 __attribute__((ext_vector_type(16)));

__device__ inline __bf16 cvt_bf16(float f) {
    unsigned u = __builtin_bit_cast(unsigned, f);
    u += 0x7fffu + ((u >> 16) & 1u);          // RTNE (finite values)
    unsigned short h = (unsigned short)(u >> 16);
    return __builtin_bit_cast(__bf16, h);
}

__device__ inline void gld16(const __bf16* g, __bf16* l) {
    __builtin_amdgcn_global_load_lds(
        (const __attribute__((address_space(1))) void*)g,
        (__attribute__((address_space(3))) void*)l, 16, 0, 0);
}

// pack two fp32 -> 2 bf16 (RTZ) in one dword: low = lo, high = hi
__device__ inline unsigned pk_bf16_rtz(float hi, float lo) {
    return __builtin_amdgcn_perm(__builtin_bit_cast(unsigned, hi),
                                 __builtin_bit_cast(unsigned, lo), 0x07060302u);
}

// ---------------------------------------------------------------------------
// Pre-pass: fused transposes.
// z < 8 : x[b=z][c][s] fp32 -> xt[b][s][c] bf16          (grid x:32, y:16)
// z >= 8: W[c][e] fp32 (weight z-8) -> Wt[e][c] bf16     (grid x:16, y:16)
// ---------------------------------------------------------------------------
__global__ __launch_bounds__(256) void transpose_xw(
    const float* __restrict__ x, __bf16* __restrict__ xt,
    const float* __restrict__ w0, const float* __restrict__ w1,
    const float* __restrict__ w2, const float* __restrict__ w3,
    __bf16* __restrict__ d0, __bf16* __restrict__ d1,
    __bf16* __restrict__ d2, __bf16* __restrict__ d3)
{
    __shared__ float T[32][33];
    const int r8 = threadIdx.x >> 5, c32 = threadIdx.x & 31;
    const int z = blockIdx.z;
    if (z < 8) {
        const int b = z, c0 = blockIdx.y * 32, s0 = blockIdx.x * 32;
#pragma unroll
        for (int i = 0; i < 4; i++)
            T[r8 + i * 8][c32] =
                x[((size_t)b * Cc + c0 + r8 + i * 8) * Ss + s0 + c32];
        __syncthreads();
#pragma unroll
        for (int i = 0; i < 4; i++)
            xt[((size_t)b * Ss + s0 + r8 + i * 8) * Cc + c0 + c32] =
                cvt_bf16(T[c32][r8 + i * 8]);
    } else {
        if (blockIdx.x >= 16) return;
        const int m = z - 8;
        const float* src = (m == 0) ? w0 : (m == 1) ? w1 : (m == 2) ? w2 : w3;
        __bf16* dst = (m == 0) ? d0 : (m == 1) ? d1 : (m == 2) ? d2 : d3;
        const int e0 = blockIdx.x * 32, c0 = blockIdx.y * 32;
#pragma unroll
        for (int i = 0; i < 4; i++)
            T[r8 + i * 8][c32] = src[(size_t)(c0 + r8 + i * 8) * Ee + e0 + c32];
        __syncthreads();
#pragma unroll
        for (int i = 0; i < 4; i++)
            dst[(size_t)(e0 + r8 + i * 8) * Cc + c0 + c32] =
                cvt_bf16(T[c32][r8 + i * 8]);
    }
}

// ---------------------------------------------------------------------------
// K1: fused QKV MFMA GEMM.  out[s][e] = xt[s][:] . Wt[e][:] + bias[e]
// Q,K -> [b][h][s][d] bf16;  V -> vt[b][h][d][S] via LDS-transpose epilogue.
// LDS union: T (34 KB, epilogue-only) overlaps As+Bs (16 KB, K-loop-only)
// -> 34 KB static => 4 blocks/CU.
// ---------------------------------------------------------------------------
__global__ __launch_bounds__(256) void qkv_mfma(
    const __bf16* __restrict__ xt,
    const __bf16* __restrict__ wqt, const __bf16* __restrict__ wkt,
    const __bf16* __restrict__ wvt,
    const float* __restrict__ bq, const float* __restrict__ bk,
    const float* __restrict__ bv,
    __bf16* __restrict__ qb, __bf16* __restrict__ kb, __bf16* __restrict__ vt)
{
    const int b = blockIdx.z;
    const int wsel = blockIdx.y >> 2;
    const int e0 = (blockIdx.y & 3) * 128;
    const int s0 = blockIdx.x * 128;
    const __bf16* A  = xt + (size_t)b * Ss * Cc;
    const __bf16* Bm = (wsel == 0) ? wqt : (wsel == 1) ? wkt : wvt;
    const float*  bias = (wsel == 0) ? bq : (wsel == 1) ? bk : bv;

    __shared__ __align__(16) char smem[128 * 136 * 2];   // 34816 B
    __bf16* As = (__bf16*)smem;                 // 128*32
    __bf16* Bs = (__bf16*)(smem + 8192);        // 128*32
    __bf16* T  = (__bf16*)smem;                 // 128*136 (epilogue)

    const int wave = threadIdx.x >> 6, lane = threadIdx.x & 63;
    const int lid = lane & 15, quad = lane >> 4;
    const int wm = wave & 1, wn = wave >> 1;
    const int srow = lane >> 2, sch = lane & 3;   // staging: 16 rows x 4 chunks

    f32x4 acc[4][4] = {};

    for (int k0 = 0; k0 < Cc; k0 += 32) {
#pragma unroll
        for (int i = 0; i < 2; i++) {
            const int inst = wave * 2 + i;        // 0..7, 16 rows each
            const int r = inst * 16 + srow;
            gld16(&A [(size_t)(s0 + r) * Cc + k0 + sch * 8], &As[inst * 512]);
            gld16(&Bm[(size_t)(e0 + r) * Cc + k0 + sch * 8], &Bs[inst * 512]);
        }
        __syncthreads();
        bf16x8 af[4], bf[4];
#pragma unroll
        for (int i = 0; i < 4; i++)
            af[i] = *(const bf16x8*)&As[(wm * 64 + i * 16 + lid) * 32 + quad * 8];
#pragma unroll
        for (int j = 0; j < 4; j++)
            bf[j] = *(const bf16x8*)&Bs[(wn * 64 + j * 16 + lid) * 32 + quad * 8];
#pragma unroll
        for (int i = 0; i < 4; i++)
#pragma unroll
            for (int j = 0; j < 4; j++)
                acc[i][j] = __builtin_amdgcn_mfma_f32_16x16x32_bf16(
                    af[i], bf[j], acc[i][j], 0, 0, 0);
        __syncthreads();
    }

    float bj[4];
#pragma unroll
    for (int j = 0; j < 4; j++) bj[j] = bias[e0 + wn * 64 + j * 16 + lid];

    if (wsel == 2) {
        // V: transpose through LDS, emit vt[b][h][d][S] with 16B stores
#pragma unroll
        for (int i = 0; i < 4; i++) {
            const int s4 = wm * 64 + i * 16 + quad * 4;
#pragma unroll
            for (int j = 0; j < 4; j++) {
                const int e_l = wn * 64 + j * 16 + lid;
                unsigned short u0 = __builtin_bit_cast(unsigned short, cvt_bf16(acc[i][j][0] + bj[j]));
                unsigned short u1 = __builtin_bit_cast(unsigned short, cvt_bf16(acc[i][j][1] + bj[j]));
                unsigned short u2 = __builtin_bit_cast(unsigned short, cvt_bf16(acc[i][j][2] + bj[j]));
                unsigned short u3 = __builtin_bit_cast(unsigned short, cvt_bf16(acc[i][j][3] + bj[j]));
                uint2 pk;
                pk.x = (unsigned)u0 | ((unsigned)u1 << 16);
                pk.y = (unsigned)u2 | ((unsigned)u3 << 16);
                *(uint2*)&T[e_l * 136 + s4] = pk;
            }
        }
        __syncthreads();
        const int t = threadIdx.x;
#pragma unroll
        for (int it = 0; it < 8; it++) {
            const int idx = t + it * 256;
            const int e_l = idx >> 4, c8 = (idx & 15) * 8;
            bf16x8 val = *(const bf16x8*)&T[e_l * 136 + c8];
            const int e_g = e0 + e_l;
            const int head = e_g >> 6, d = e_g & 63;
            *(bf16x8*)&vt[(((size_t)b * nHd + head) * Hd + d) * Ss + s0 + c8] = val;
        }
    } else {
        __bf16* outp = (wsel == 0) ? qb : kb;
#pragma unroll
        for (int i = 0; i < 4; i++) {
#pragma unroll
            for (int j = 0; j < 4; j++) {
                const int e1 = e0 + wn * 64 + j * 16 + lid;
                const int head = e1 >> 6, d = e1 & 63;
#pragma unroll
                for (int r = 0; r < 4; r++) {
                    const int s1 = s0 + wm * 64 + i * 16 + quad * 4 + r;
                    outp[(((size_t)b * nHd + head) * Ss + s1) * Hd + d] =
                        cvt_bf16(acc[i][j][r] + bj[j]);
                }
            }
        }
    }
}

// ---------------------------------------------------------------------------
// K2: MFMA flash attention, S^T orientation, no-max softmax, 128-key tiles.
// q,k: [bh][S][64] bf16; vt: [bh][64][S] bf16.
// Block = 128 q-rows (4 waves x 32), 8 iterations of 128 keys.
// LDS 64 KB: Ks[128][64] + Vs[64][128] + per-wave Ps[32][128], XOR-swizzled.
// ---------------------------------------------------------------------------
__global__ __launch_bounds__(256, 2) void attn_mfma(
    const __bf16* __restrict__ q, const __bf16* __restrict__ k,
    const __bf16* __restrict__ vt, __bf16* __restrict__ attn_out)
{
    const int bh = blockIdx.x;          // bh-major: q-tiles of one bh -> one XCD
    const int s0 = blockIdx.y * 128;
    const __bf16* qp = q  + (size_t)bh * Ss * Hd;
    const __bf16* kp = k  + (size_t)bh * Ss * Hd;
    const __bf16* vp = vt + (size_t)bh * Hd * Ss;

    __shared__ __align__(16) __bf16 Ks[128 * 64];     // [sk][d]
    __shared__ __align__(16) __bf16 Vs[64 * 128];     // [d][sk]
    __shared__ __align__(16) __bf16 Ps[4][32 * 128];  // per-wave [sq][sk]

    const int wave = threadIdx.x >> 6, lane = threadIdx.x & 63;
    const int nl = lane & 31, h = lane >> 5;
    __bf16* PsW = Ps[wave];

    const int sq = s0 + wave * 32 + nl;
    bf16x8 qf[4];
#pragma unroll
    for (int kk2 = 0; kk2 < 4; kk2++)
        qf[kk2] = *(const bf16x8*)&qp[(size_t)sq * Hd + kk2 * 16 + h * 8];

    f32x16 oacc[2] = {};
    float rs = 0.0f;
    const float cexp = 0.125f * 1.44269504f;   // scale * log2(e)

    const int srow8 = lane >> 3, sch8 = lane & 7;     // K staging
    const int srow4 = lane >> 4, sch16 = lane & 15;   // V staging

    for (int kt = 0; kt < 8; kt++) {
#pragma unroll
        for (int i = 0; i < 4; i++) {
            const int inst = wave * 4 + i;            // 0..15
            const int rK = inst * 8 + srow8;          // K: 8 rows/inst
            gld16(&kp[(size_t)(kt * 128 + rK) * Hd + ((sch8 ^ (rK & 7)) * 8)],
                  &Ks[inst * 512]);
            const int dR = inst * 4 + srow4;          // V: 4 rows/inst
            gld16(&vp[(size_t)dR * Ss + kt * 128 + ((sch16 ^ (dR & 15)) * 8)],
                  &Vs[inst * 512]);                   // 512 el = 1024 B/inst
        }
        __syncthreads();

        // scores: S^T[sk][sq], 4 sk-tiles of 32, K-dim = d (4 steps of 16)
        f32x16 sc[4] = {};
#pragma unroll
        for (int kk2 = 0; kk2 < 4; kk2++) {
#pragma unroll
            for (int mt = 0; mt < 4; mt++) {
                bf16x8 kf = *(const bf16x8*)&Ks[(mt * 32 + nl) * 64 +
                                                (((2 * kk2 + h) ^ (nl & 7)) * 8)];
                sc[mt] = __builtin_amdgcn_mfma_f32_32x32x16_bf16(
                    kf, qf[kk2], sc[mt], 0, 0, 0);
            }
        }

        // no-max softmax: p = exp2(s*c); in-lane row-sum; pack -> Ps
#pragma unroll
        for (int mt = 0; mt < 4; mt++) {
            float p[16];
#pragma unroll
            for (int r = 0; r < 16; r++) {
                p[r] = __builtin_amdgcn_exp2f(sc[mt][r] * cexp);
                rs += p[r];
            }
#pragma unroll
            for (int g = 0; g < 4; g++) {
                uint2 pk;
                pk.x = pk_bf16_rtz(p[4 * g + 1], p[4 * g + 0]);
                pk.y = pk_bf16_rtz(p[4 * g + 3], p[4 * g + 2]);
                const int gr = (mt * 8 + 2 * g + h) ^ ((nl & 15) << 1);
                *(uint2*)&PsW[nl * 128 + gr * 4] = pk;
            }
        }

        // PV: O[sq][d] = P[sq][sk] . V[sk][d]
#pragma unroll
        for (int kk = 0; kk < 8; kk++) {
            const int cp = (kk * 2 + h) ^ (nl & 15);
            bf16x8 pf = *(const bf16x8*)&PsW[nl * 128 + cp * 8];
#pragma unroll
            for (int dt = 0; dt < 2; dt++) {
                bf16x8 vf = *(const bf16x8*)&Vs[(dt * 32 + nl) * 128 +
                                                (((kk * 2 + h) ^ (nl & 15)) * 8)];
                oacc[dt] = __builtin_amdgcn_mfma_f32_32x32x16_bf16(
                    pf, vf, oacc[dt], 0, 0, 0);
            }
        }
        __syncthreads();
    }

    // epilogue: l = cross-half sum of rs; normalize; store [b][s][e]
    rs += __shfl_xor(rs, 32, 64);
    const float inv = 1.0f / rs;
    const int b = bh >> 3, head = bh & 7;
#pragma unroll
    for (int r = 0; r < 16; r++) {
        const int rowq = (r & 3) + 8 * (r >> 2) + 4 * h;
        const float invr = __shfl(inv, rowq, 64);
        const int s1 = s0 + wave * 32 + rowq;
#pragma unroll
        for (int dt = 0; dt < 2; dt++)
            attn_out[((size_t)b * Ss + s1) * Ee + head * Hd + dt * 32 + nl] =
                cvt_bf16(oacc[dt][r] * invr);
    }
}

// ---------------------------------------------------------------------------
// K3: output projection, M=eo N=s; y[b][eo][s] bf16 (+bias+residual).
// ---------------------------------------------------------------------------
__global__ __launch_bounds__(256) void outproj_mfma(
    const __bf16* __restrict__ attnb, const __bf16* __restrict__ wot,
    const float* __restrict__ bo, const float* __restrict__ xin,
    __bf16* __restrict__ y)
{
    const int b  = blockIdx.z;
    const int e0 = blockIdx.y * 128;   // eo
    const int s0 = blockIdx.x * 128;
    const __bf16* Bm = attnb + (size_t)b * Ss * Ee;   // [s][ei]

    __shared__ __align__(16) __bf16 As[128 * 32];
    __shared__ __align__(16) __bf16 Bs[128 * 32];

    const int wave = threadIdx.x >> 6, lane = threadIdx.x & 63;
    const int lid = lane & 15, quad = lane >> 4;
    const int wm = wave & 1, wn = wave >> 1;
    const int srow = lane >> 2, sch = lane & 3;

    f32x4 acc[4][4] = {};

    for (int k0 = 0; k0 < Ee; k0 += 32) {
#pragma unroll
        for (int i = 0; i < 2; i++) {
            const int inst = wave * 2 + i;
            const int r = inst * 16 + srow;
            gld16(&wot[(size_t)(e0 + r) * Ee + k0 + sch * 8], &As[inst * 512]);
            gld16(&Bm [(size_t)(s0 + r) * Ee + k0 + sch * 8], &Bs[inst * 512]);
        }
        __syncthreads();
        bf16x8 af[4], bf[4];
#pragma unroll
        for (int i = 0; i < 4; i++)
            af[i] = *(const bf16x8*)&As[(wm * 64 + i * 16 + lid) * 32 + quad * 8];
#pragma unroll
        for (int j = 0; j < 4; j++)
            bf[j] = *(const bf16x8*)&Bs[(wn * 64 + j * 16 + lid) * 32 + quad * 8];
#pragma unroll
        for (int i = 0; i < 4; i++)
#pragma unroll
            for (int j = 0; j < 4; j++)
                acc[i][j] = __builtin_amdgcn_mfma_f32_16x16x32_bf16(
                    af[i], bf[j], acc[i][j], 0, 0, 0);
        __syncthreads();
    }

#pragma unroll
    for (int i = 0; i < 4; i++) {
#pragma unroll
        for (int r = 0; r < 4; r++) {
            const int eo1 = e0 + wm * 64 + i * 16 + quad * 4 + r;
            const float bb = bo[eo1];
#pragma unroll
            for (int j = 0; j < 4; j++) {
                const int s1 = s0 + wn * 64 + j * 16 + lid;
                const size_t idx = ((size_t)b * Ee + eo1) * Ss + s1;
                y[idx] = cvt_bf16(acc[i][j][r] + bb + xin[idx]);
            }
        }
    }
}

// ---------------------------------------------------------------------------
// K4: GroupNorm.  y bf16 [B][E][S], contiguous per group; out fp32.
// ---------------------------------------------------------------------------
__global__ __launch_bounds__(256) void gnorm_kernel(
    const __bf16* __restrict__ y, const float* __restrict__ gamma,
    const float* __restrict__ beta, float* __restrict__ out)
{
    const int bg = blockIdx.x;
    const int b = bg >> 5, g = bg & 31;
    const size_t base = ((size_t)b * Ee + g * Cpg) * Ss;
    const bf16x8* y8 = (const bf16x8*)(y + base);
    constexpr int N8 = (Cpg * Ss) / 8;   // 2048

    float s = 0.f, s2 = 0.f;
    for (int i = threadIdx.x; i < N8; i += 256) {
        bf16x8 vv = y8[i];
#pragma unroll
        for (int j = 0; j < 8; j++) {
            const float f = (float)vv[j];
            s += f; s2 += f * f;
        }
    }
#pragma unroll
    for (int off = 32; off > 0; off >>= 1) {
        s  += __shfl_down(s, off, 64);
        s2 += __shfl_down(s2, off, 64);
    }
    __shared__ float red[8];
    __shared__ float stats[2];
    const int lane = threadIdx.x & 63, wid = threadIdx.x >> 6;
    if (lane == 0) { red[wid] = s; red[4 + wid] = s2; }
    __syncthreads();
    if (threadIdx.x == 0) {
        float ts  = red[0] + red[1] + red[2] + red[3];
        float ts2 = red[4] + red[5] + red[6] + red[7];
        float mean = ts / (float)(Cpg * Ss);
        float var  = ts2 / (float)(Cpg * Ss) - mean * mean;
        stats[0] = mean;
        stats[1] = rsqrtf(var + 1e-5f);
    }
    __syncthreads();
    const float mean = stats[0], rstd = stats[1];
    for (int i = threadIdx.x; i < N8; i += 256) {
        bf16x8 vv = y8[i];
        const int c = g * Cpg + (i >> 7);   // 128 bf16x8 per channel
        const float gm = gamma[c] * rstd;
        const float bt = beta[c];
        f32x4 r0, r1;
#pragma unroll
        for (int j = 0; j < 4; j++) r0[j] = ((float)vv[j] - mean) * gm + bt;
#pragma unroll
        for (int j = 0; j < 4; j++) r1[j] = ((float)vv[4 + j] - mean) * gm + bt;
        *(f32x4*)&out[base + (size_t)i * 8]     = r0;
        *(f32x4*)&out[base + (size_t)i * 8 + 4] = r1;
    }
}

// ---------------------------------------------------------------------------
extern "C" void kernel_launch(void* const* d_in, const int* in_sizes, int n_in,
                              void* d_out, int out_size, void* d_ws, size_t ws_size,
                              hipStream_t stream)
{
    const float* x     = (const float*)d_in[0];
    const float* Wq    = (const float*)d_in[1];
    const float* bq    = (const float*)d_in[2];
    const float* Wk    = (const float*)d_in[3];
    const float* bk    = (const float*)d_in[4];
    const float* Wv    = (const float*)d_in[5];
    const float* bv    = (const float*)d_in[6];
    const float* Wo    = (const float*)d_in[7];
    const float* bo    = (const float*)d_in[8];
    const float* gamma = (const float*)d_in[9];
    const float* beta  = (const float*)d_in[10];
    float* out = (float*)d_out;

    // workspace layout (bytes)
    char* ws = (char*)d_ws;
    __bf16* xt    = (__bf16*)ws;                          //  8 MiB
    __bf16* wqt   = (__bf16*)(ws + (8u << 20));           // 512 KiB
    __bf16* wkt   = (__bf16*)(ws + (8u << 20) + (512u << 10));
    __bf16* wvt   = (__bf16*)(ws + (9u << 20));
    __bf16* wot   = (__bf16*)(ws + (9u << 20) + (512u << 10));
    __bf16* qb    = (__bf16*)(ws + (10u << 20));          //  8 MiB
    __bf16* kb    = (__bf16*)(ws + (18u << 20));          //  8 MiB
    __bf16* vtb   = (__bf16*)(ws + (26u << 20));          //  8 MiB (V^T)
    __bf16* attnb = (__bf16*)(ws + (34u << 20));          //  8 MiB
    __bf16* yb    = (__bf16*)(ws + (42u << 20));          //  8 MiB

    transpose_xw<<<dim3(32, 16, 12), 256, 0, stream>>>(
        x, xt, Wq, Wk, Wv, Wo, wqt, wkt, wvt, wot);

    qkv_mfma<<<dim3(Ss / 128, 12, Bn), 256, 0, stream>>>(
        xt, wqt, wkt, wvt, bq, bk, bv, qb, kb, vtb);

    attn_mfma<<<dim3(Bn * nHd, Ss / 128), 256, 0, stream>>>(qb, kb, vtb, attnb);

    outproj_mfma<<<dim3(Ss / 128, Ee / 128, Bn), 256, 0, stream>>>(
        attnb, wot, bo, x, yb);

    gnorm_kernel<<<Bn * Gg, 256, 0, stream>>>(yb, gamma, beta, out);
}